// Round 11
// baseline (152.850 us; speedup 1.0000x reference)
//
#include <hip/hip_runtime.h>
#include <math.h>

#define B    64
#define NPG  1024
#define KEIG 32
#define DIN  512
#define DOUT 512
#define NPART 8   // k2 n-chunk partials

typedef float f32x4 __attribute__((ext_vector_type(4)));

__device__ __forceinline__ float rsum32(float v) {
    v += __shfl_xor(v, 1, 32);
    v += __shfl_xor(v, 2, 32);
    v += __shfl_xor(v, 4, 32);
    v += __shfl_xor(v, 8, 32);
    v += __shfl_xor(v, 16, 32);
    return v;
}
__device__ __forceinline__ float rmax32(float v) {
    v = fmaxf(v, __shfl_xor(v, 1, 32));
    v = fmaxf(v, __shfl_xor(v, 2, 32));
    v = fmaxf(v, __shfl_xor(v, 4, 32));
    v = fmaxf(v, __shfl_xor(v, 8, 32));
    v = fmaxf(v, __shfl_xor(v, 16, 32));
    return v;
}

// ---------------------------------------------------------------------------
// Kernel 1: feature-parallel encoder + MHSA + filter head. (unchanged, ~8us)
// ---------------------------------------------------------------------------
__global__ __launch_bounds__(1024) void k1_filters(
    const float* __restrict__ eigenvalues,
    const float* __restrict__ W1,  const float* __restrict__ b1,
    const float* __restrict__ g1,  const float* __restrict__ be1,
    const float* __restrict__ W2,  const float* __restrict__ b2,
    const float* __restrict__ g2,  const float* __restrict__ be2,
    const float* __restrict__ Wqkv,const float* __restrict__ bqkv,
    const float* __restrict__ Wo,  const float* __restrict__ bo,
    const float* __restrict__ Wf1, const float* __restrict__ bf1,
    const float* __restrict__ Wf2, const float* __restrict__ bf2,
    float* __restrict__ filters)
{
    __shared__ float wts[224][33];
    __shared__ float hA[KEIG][33];
    __shared__ float hB[KEIG][33];
    __shared__ float qkv[KEIG][97];
    __shared__ float attn[4 * 1064];

    const int t = threadIdx.x;
    const int k = t >> 5;
    const int j = t & 31;
    const int b = blockIdx.x;

    {
        const int row = t >> 5, i = t & 31;
        wts[row][i]       = W2[t];
        wts[32 + row][i]  = Wqkv[t];
        wts[64 + row][i]  = Wqkv[1024 + t];
        wts[96 + row][i]  = Wqkv[2048 + t];
        wts[128 + row][i] = Wo[t];
        wts[160 + row][i] = Wf1[t];
        wts[192 + row][i] = Wf1[1024 + t];
    }

    const float ev = eigenvalues[b * KEIG + k];
    float h1 = ev * W1[j] + b1[j];
    {
        float m = rsum32(h1) * (1.f / 32.f);
        float d = h1 - m;
        float q = rsum32(d * d);
        float r = rsqrtf(q * (1.f / 32.f) + 1e-5f);
        h1 = fmaxf(d * r * g1[j] + be1[j], 0.f);
    }
    hA[k][j] = h1;
    __syncthreads();

    {
        float a = b2[j];
        #pragma unroll
        for (int i = 0; i < 32; ++i) a += hA[k][i] * wts[j][i];
        float m = rsum32(a) * (1.f / 32.f);
        float d = a - m;
        float q = rsum32(d * d);
        float r = rsqrtf(q * (1.f / 32.f) + 1e-5f);
        hB[k][j] = d * r * g2[j] + be2[j];
    }
    __syncthreads();

    {
        float aq = bqkv[j], ak = bqkv[32 + j], av = bqkv[64 + j];
        #pragma unroll
        for (int i = 0; i < 32; ++i) {
            float hv = hB[k][i];
            aq += hv * wts[32 + j][i];
            ak += hv * wts[64 + j][i];
            av += hv * wts[96 + j][i];
        }
        qkv[k][j]      = aq;
        qkv[k][32 + j] = ak;
        qkv[k][64 + j] = av;
    }
    __syncthreads();

    {
        const float inv = 0.35355339059327373f;
        float sc[4];
        #pragma unroll
        for (int hh = 0; hh < 4; ++hh) {
            float s = 0.f;
            #pragma unroll
            for (int d2 = 0; d2 < 8; ++d2)
                s += qkv[k][hh * 8 + d2] * qkv[j][32 + hh * 8 + d2];
            sc[hh] = s * inv;
        }
        #pragma unroll
        for (int hh = 0; hh < 4; ++hh) {
            float mx  = rmax32(sc[hh]);
            float e   = __expf(sc[hh] - mx);
            float den = rsum32(e);
            attn[hh * 1064 + k * 33 + j] = e / den;
        }
    }
    __syncthreads();

    {
        const int hh = j >> 3;
        float c = 0.f;
        #pragma unroll
        for (int k2 = 0; k2 < 32; ++k2)
            c += attn[hh * 1064 + k * 33 + k2] * qkv[k2][64 + j];
        hA[k][j] = c;
    }
    __syncthreads();

    {
        float o = bo[j];
        #pragma unroll
        for (int i = 0; i < 32; ++i) o += hA[k][i] * wts[128 + j][i];
        hB[k][j] = o;
    }
    __syncthreads();

    {
        float r0 = bf1[j], r1 = bf1[32 + j];
        #pragma unroll
        for (int i = 0; i < 32; ++i) {
            float ov = hB[k][i];
            r0 += ov * wts[160 + j][i];
            r1 += ov * wts[192 + j][i];
        }
        float fp = fmaxf(r0, 0.f) * Wf2[j] + fmaxf(r1, 0.f) * Wf2[32 + j];
        fp = rsum32(fp);
        if (j == 0) filters[b * KEIG + k] = tanhf(fp + bf2[0]);
    }
}

// ---------------------------------------------------------------------------
// Kernel 2: xfp[nc][b][k][d] = sum_{n in 128-row chunk} vg[n,k]*x[n,d]
// (unchanged; ~30us, near its 176MB traffic roofline)
// ---------------------------------------------------------------------------
__global__ __launch_bounds__(256) void k2_xfreq_partial(
    const float* __restrict__ x, const float* __restrict__ eigvec,
    float* __restrict__ xfp)
{
    __shared__ float vtile[128][32];
    const int t  = threadIdx.x;
    const int b  = blockIdx.x >> 4;
    const int nc = (blockIdx.x >> 1) & 7;
    const int dh = blockIdx.x & 1;
    const int kq = t >> 6;
    const int ds = t & 63;
    const int d  = dh * 256 + ds * 4;
    const int n0 = nc * 128;

    const float* vb = eigvec + ((size_t)(b * NPG + n0)) * KEIG;
    #pragma unroll
    for (int e = 0; e < 16; ++e) {
        int idx = t + e * 256;
        ((float*)vtile)[idx] = vb[idx];
    }
    __syncthreads();

    float4 acc[8];
    #pragma unroll
    for (int i = 0; i < 8; ++i) acc[i] = make_float4(0.f, 0.f, 0.f, 0.f);

    const float* xb = x + ((size_t)(b * NPG + n0)) * DIN + d;
    #pragma unroll 4
    for (int n = 0; n < 128; ++n) {
        float4 xv = *(const float4*)(xb + (size_t)n * DIN);
        const float4* vp = (const float4*)&vtile[n][kq * 8];
        float4 v0 = vp[0], v1 = vp[1];
        acc[0].x += v0.x * xv.x; acc[0].y += v0.x * xv.y; acc[0].z += v0.x * xv.z; acc[0].w += v0.x * xv.w;
        acc[1].x += v0.y * xv.x; acc[1].y += v0.y * xv.y; acc[1].z += v0.y * xv.z; acc[1].w += v0.y * xv.w;
        acc[2].x += v0.z * xv.x; acc[2].y += v0.z * xv.y; acc[2].z += v0.z * xv.z; acc[2].w += v0.z * xv.w;
        acc[3].x += v0.w * xv.x; acc[3].y += v0.w * xv.y; acc[3].z += v0.w * xv.z; acc[3].w += v0.w * xv.w;
        acc[4].x += v1.x * xv.x; acc[4].y += v1.x * xv.y; acc[4].z += v1.x * xv.z; acc[4].w += v1.x * xv.w;
        acc[5].x += v1.y * xv.x; acc[5].y += v1.y * xv.y; acc[5].z += v1.y * xv.z; acc[5].w += v1.y * xv.w;
        acc[6].x += v1.z * xv.x; acc[6].y += v1.z * xv.y; acc[6].z += v1.z * xv.z; acc[6].w += v1.z * xv.w;
        acc[7].x += v1.w * xv.x; acc[7].y += v1.w * xv.y; acc[7].z += v1.w * xv.z; acc[7].w += v1.w * xv.w;
    }

    #pragma unroll
    for (int kk = 0; kk < 8; ++kk) {
        int kg = kq * 8 + kk;
        *(float4*)(xfp + (((size_t)nc * B + b) * KEIG + kg) * DIN + d) = acc[kk];
    }
}

// ---------------------------------------------------------------------------
// Kernel 2b: F[m][d] = filters[m] * sum_nc xfp[nc][m][d].  (~7us)
// ---------------------------------------------------------------------------
__global__ __launch_bounds__(256) void k2b_combine(
    const float* __restrict__ xfp, const float* __restrict__ filters,
    float* __restrict__ F)
{
    const int t = threadIdx.x;
    const int m = blockIdx.x * 2 + (t >> 7);
    const int dp = (t & 127) * 4;

    const float* base = xfp + (size_t)m * DIN + dp;
    float4 s = *(const float4*)base;
    #pragma unroll
    for (int q = 1; q < NPART; ++q) {
        float4 sq = *(const float4*)(base + (size_t)q * (B * KEIG * DIN));
        s.x += sq.x; s.y += sq.y; s.z += sq.z; s.w += sq.w;
    }
    const float f = filters[m];
    float4 o = make_float4(s.x * f, s.y * f, s.z * f, s.w * f);
    *(float4*)(F + (size_t)m * DIN + dp) = o;
}

// ---------------------------------------------------------------------------
// Kernel 3: pure GEMM  G[m][o] = sum_d F[m][d] * Wp[o][d].  (~15us)
// ---------------------------------------------------------------------------
__global__ __launch_bounds__(256) void k3_G(
    const float* __restrict__ F, const float* __restrict__ Wp,
    float* __restrict__ G)
{
    __shared__ float a_lds[64][65];
    __shared__ float b_lds[64][65];

    const int t   = threadIdx.x;
    const int mt  = blockIdx.x >> 3;
    const int ot  = blockIdx.x & 7;
    const int m0  = mt * 64;
    const int o0  = ot * 64;
    const int tr  = t >> 4;
    const int tc  = t & 15;
    const int col4 = tc * 4;

    float acc[4][4] = {{0.f}};

    for (int d0 = 0; d0 < DIN; d0 += 64) {
        __syncthreads();
        #pragma unroll
        for (int p = 0; p < 4; ++p) {
            int r = p * 16 + tr;
            float4 s = *(const float4*)(F + (size_t)(m0 + r) * DIN + d0 + col4);
            a_lds[r][col4 + 0] = s.x;
            a_lds[r][col4 + 1] = s.y;
            a_lds[r][col4 + 2] = s.z;
            a_lds[r][col4 + 3] = s.w;
        }
        #pragma unroll
        for (int p = 0; p < 4; ++p) {
            int r = p * 16 + tr;
            float4 w = *(const float4*)(Wp + (size_t)(o0 + r) * DIN + d0 + col4);
            b_lds[r][col4 + 0] = w.x;
            b_lds[r][col4 + 1] = w.y;
            b_lds[r][col4 + 2] = w.z;
            b_lds[r][col4 + 3] = w.w;
        }
        __syncthreads();
        #pragma unroll 4
        for (int dd = 0; dd < 64; ++dd) {
            float a0 = a_lds[tr * 4 + 0][dd];
            float a1 = a_lds[tr * 4 + 1][dd];
            float a2 = a_lds[tr * 4 + 2][dd];
            float a3 = a_lds[tr * 4 + 3][dd];
            float b0 = b_lds[tc * 4 + 0][dd];
            float b1 = b_lds[tc * 4 + 1][dd];
            float b2 = b_lds[tc * 4 + 2][dd];
            float b3 = b_lds[tc * 4 + 3][dd];
            acc[0][0] += a0 * b0; acc[0][1] += a0 * b1; acc[0][2] += a0 * b2; acc[0][3] += a0 * b3;
            acc[1][0] += a1 * b0; acc[1][1] += a1 * b1; acc[1][2] += a1 * b2; acc[1][3] += a1 * b3;
            acc[2][0] += a2 * b0; acc[2][1] += a2 * b1; acc[2][2] += a2 * b2; acc[2][3] += a2 * b3;
            acc[3][0] += a3 * b0; acc[3][1] += a3 * b1; acc[3][2] += a3 * b2; acc[3][3] += a3 * b3;
        }
    }
    #pragma unroll
    for (int i = 0; i < 4; ++i) {
        float4 v = make_float4(acc[i][0], acc[i][1], acc[i][2], acc[i][3]);
        *(float4*)(G + (size_t)(m0 + tr * 4 + i) * DOUT + o0 + col4) = v;
    }
}

// ---------------------------------------------------------------------------
// Kernel 3s (new): per-(b, o-slice) LN-statistics partials.
//   M_p = G_slice G_slice^T (32x32), gmu_p = G_slice·1, c_p = G_slice·bp,
//   bpm_p = sum bp, bp2_p = sum bp^2.   (analytic LN: mean/var of
//   y = vg·G + bp are quadratic forms in vg -> no per-row column reductions)
// grid = B*8 = 512 blocks. Bank-rotated LDS reads (pad 68 + oe=(o+i0)&63):
// gi broadcast per 8-lane group, gj 2-way max.
// ---------------------------------------------------------------------------
__global__ __launch_bounds__(256) void k3s_stats(
    const float* __restrict__ G, const float* __restrict__ bp,
    float* __restrict__ stats)
{
    __shared__ float gs[32][68];
    __shared__ float bps[64];
    const int b  = blockIdx.x >> 3;
    const int sl = blockIdx.x & 7;
    const int o0 = sl * 64;
    const int t  = threadIdx.x;

    #pragma unroll
    for (int e = 0; e < 2; ++e) {
        int fi = t + e * 256;        // 512 float4 slots
        int k  = fi >> 4;            // 16 float4 per row
        int c4 = fi & 15;
        float4 g = *(const float4*)(G + ((size_t)(b * KEIG + k)) * DOUT + o0 + c4 * 4);
        *(float4*)&gs[k][c4 * 4] = g;
    }
    if (t < 64) bps[t] = bp[o0 + t];
    __syncthreads();

    const int i0 = t >> 3;   // 0..31
    const int j0 = t & 7;    // 0..7 -> cols j0, j0+8, j0+16, j0+24
    float m0 = 0.f, m1 = 0.f, m2 = 0.f, m3 = 0.f, gm = 0.f, cc = 0.f;
    #pragma unroll 8
    for (int o = 0; o < 64; ++o) {
        int oe = (o + i0) & 63;
        float gi = gs[i0][oe];
        m0 = fmaf(gi, gs[j0][oe],      m0);
        m1 = fmaf(gi, gs[j0 + 8][oe],  m1);
        m2 = fmaf(gi, gs[j0 + 16][oe], m2);
        m3 = fmaf(gi, gs[j0 + 24][oe], m3);
        gm += gi;
        cc = fmaf(gi, bps[oe], cc);
    }
    float* Sb = stats + (size_t)(b * 8 + sl) * 1152;
    Sb[i0 * 32 + j0]      = m0;
    Sb[i0 * 32 + j0 + 8]  = m1;
    Sb[i0 * 32 + j0 + 16] = m2;
    Sb[i0 * 32 + j0 + 24] = m3;
    if (j0 == 0) { Sb[1024 + i0] = gm; Sb[1056 + i0] = cc; }
    if (t == 0) {
        float s1 = 0.f, s2 = 0.f;
        for (int o = 0; o < 64; ++o) { float v = bps[o]; s1 += v; s2 += v * v; }
        Sb[1088] = s1; Sb[1089] = s2;
    }
}

// ---------------------------------------------------------------------------
// Kernel 3r (new): reduce the 8 slice-partials, then per-row stats:
//   mean_n = vg_n·gmu + bpm;  E[y^2] = vg_n^T M vg_n + 2 vg_n·c + bp2
//   rowstats[n] = (mean, rsqrt(var+eps)).  grid = B*4, 1 row/thread.
// ---------------------------------------------------------------------------
__global__ __launch_bounds__(256) void k3r_rowstats(
    const float* __restrict__ eigvec, const float* __restrict__ stats,
    float2* __restrict__ rowstats)
{
    __shared__ float Ms[1090];
    const int b  = blockIdx.x >> 2;
    const int rc = blockIdx.x & 3;
    const int t  = threadIdx.x;

    for (int e = t; e < 1090; e += 256) {
        float s = 0.f;
        #pragma unroll
        for (int sl = 0; sl < 8; ++sl)
            s += stats[(size_t)(b * 8 + sl) * 1152 + e];
        Ms[e] = s * (1.f / 512.f);
    }
    __syncthreads();

    const int n = b * NPG + rc * 256 + t;
    const float* vr = eigvec + (size_t)n * KEIG;
    float v[32];
    #pragma unroll
    for (int e = 0; e < 8; ++e) {
        float4 vv = *(const float4*)(vr + e * 4);
        v[e * 4 + 0] = vv.x; v[e * 4 + 1] = vv.y;
        v[e * 4 + 2] = vv.z; v[e * 4 + 3] = vv.w;
    }
    float qf = 0.f, mean = 0.f, vc = 0.f;
    #pragma unroll
    for (int i = 0; i < 32; ++i) {
        float mi = 0.f;
        #pragma unroll
        for (int j4 = 0; j4 < 8; ++j4) {
            float4 mr = *(const float4*)&Ms[i * 32 + j4 * 4];
            mi = fmaf(mr.x, v[j4 * 4 + 0], mi);
            mi = fmaf(mr.y, v[j4 * 4 + 1], mi);
            mi = fmaf(mr.z, v[j4 * 4 + 2], mi);
            mi = fmaf(mr.w, v[j4 * 4 + 3], mi);
        }
        qf = fmaf(v[i], mi, qf);
    }
    #pragma unroll
    for (int i4 = 0; i4 < 8; ++i4) {
        float4 gm = *(const float4*)&Ms[1024 + i4 * 4];
        float4 cv = *(const float4*)&Ms[1056 + i4 * 4];
        mean = fmaf(gm.x, v[i4 * 4 + 0], mean);
        mean = fmaf(gm.y, v[i4 * 4 + 1], mean);
        mean = fmaf(gm.z, v[i4 * 4 + 2], mean);
        mean = fmaf(gm.w, v[i4 * 4 + 3], mean);
        vc   = fmaf(cv.x, v[i4 * 4 + 0], vc);
        vc   = fmaf(cv.y, v[i4 * 4 + 1], vc);
        vc   = fmaf(cv.z, v[i4 * 4 + 2], vc);
        vc   = fmaf(cv.w, v[i4 * 4 + 3], vc);
    }
    mean += Ms[1088];
    float e2  = qf + 2.f * vc + Ms[1089];
    float var = e2 - mean * mean;
    rowstats[n] = make_float2(mean, rsqrtf(var + 1e-5f));
}

// ---------------------------------------------------------------------------
// Kernel 4 (v7): out[n,hc] = (vg[n,:]·G[b][:,hc] + bp - mean_n)*rstd_n*gp + bep
// Analytic LN -> NO cross-lane reductions, NO in-loop barriers, and cols
// split across blocks: grid = B*16*2 = 2048, block = 64 rows x 256 cols.
// LDS 41 KB -> 3 blocks/CU = 12 waves (prev 8), G half-tile b128 per 16 FMA,
// each row's stores independent (prev: 12-op shfl chain before every store).
// ---------------------------------------------------------------------------
__global__ __launch_bounds__(256) void k4_out(
    const float* __restrict__ eigvec, const float* __restrict__ G,
    const float2* __restrict__ rowstats,
    const float* __restrict__ bp, const float* __restrict__ gp,
    const float* __restrict__ bep, float* __restrict__ out)
{
    __shared__ float gsh[KEIG][256];   // 32 KB: half of G[b]'s columns
    __shared__ float vgt[KEIG][68];    // transposed vg tile
    __shared__ float2 rsh[64];

    const int t    = threadIdx.x;
    const int b    = blockIdx.x >> 5;
    const int rc   = (blockIdx.x >> 1) & 15;
    const int half = blockIdx.x & 1;
    const int n0   = rc * 64;
    const int hc0  = half * 256;

    #pragma unroll
    for (int e = 0; e < 8; ++e) {
        int fi = t + e * 256;          // 2048 float4 slots
        int k  = fi >> 6;              // 64 float4 per row
        int c4 = fi & 63;
        float4 g = *(const float4*)(G + ((size_t)(b * KEIG + k)) * DOUT + hc0 + c4 * 4);
        *(float4*)&gsh[k][c4 * 4] = g;
    }
    const float* vb = eigvec + ((size_t)(b * NPG + n0)) * KEIG;
    #pragma unroll
    for (int e = 0; e < 8; ++e) {
        int idx = t + e * 256;
        vgt[idx & 31][idx >> 5] = vb[idx];
    }
    if (t < 64) rsh[t] = rowstats[b * NPG + n0 + t];
    __syncthreads();   // the ONLY barrier

    const int w  = t >> 6;
    const int l  = t & 63;
    const int c0 = 4 * l;

    const float4 bpv = *(const float4*)(bp + hc0 + c0);
    const float4 gpv = *(const float4*)(gp + hc0 + c0);
    const float4 bev = *(const float4*)(bep + hc0 + c0);

    for (int gq = 0; gq < 4; ++gq) {
        const int rbase = w * 16 + gq * 4;
        float4 aa[4];
        #pragma unroll
        for (int r = 0; r < 4; ++r) aa[r] = bpv;

        #pragma unroll 8
        for (int k = 0; k < KEIG; ++k) {
            const float4 g  = *(const float4*)&gsh[k][c0];
            const float4 vv = *(const float4*)&vgt[k][rbase];
            const float vr[4] = {vv.x, vv.y, vv.z, vv.w};
            #pragma unroll
            for (int r = 0; r < 4; ++r) {
                aa[r].x = fmaf(vr[r], g.x, aa[r].x);
                aa[r].y = fmaf(vr[r], g.y, aa[r].y);
                aa[r].z = fmaf(vr[r], g.z, aa[r].z);
                aa[r].w = fmaf(vr[r], g.w, aa[r].w);
            }
        }

        #pragma unroll
        for (int r = 0; r < 4; ++r) {
            float2 ms = rsh[rbase + r];
            float4 o4;
            o4.x = (aa[r].x - ms.x) * ms.y * gpv.x + bev.x;
            o4.y = (aa[r].y - ms.x) * ms.y * gpv.y + bev.y;
            o4.z = (aa[r].z - ms.x) * ms.y * gpv.z + bev.z;
            o4.w = (aa[r].w - ms.x) * ms.y * gpv.w + bev.w;
            size_t row = (size_t)b * NPG + n0 + rbase + r;
            *(float4*)(out + row * DOUT + hc0 + c0) = o4;
        }
    }
}

// ---------------------------------------------------------------------------
extern "C" void kernel_launch(void* const* d_in, const int* in_sizes, int n_in,
                              void* d_out, int out_size, void* d_ws, size_t ws_size,
                              hipStream_t stream) {
    (void)in_sizes; (void)n_in; (void)out_size; (void)ws_size;
    const float* x    = (const float*)d_in[0];
    const float* vg   = (const float*)d_in[1];
    const float* ev   = (const float*)d_in[2];
    const float* W1   = (const float*)d_in[5];
    const float* b1   = (const float*)d_in[6];
    const float* g1   = (const float*)d_in[7];
    const float* be1  = (const float*)d_in[8];
    const float* W2   = (const float*)d_in[9];
    const float* b2   = (const float*)d_in[10];
    const float* g2   = (const float*)d_in[11];
    const float* be2  = (const float*)d_in[12];
    const float* Wqkv = (const float*)d_in[13];
    const float* bqkv = (const float*)d_in[14];
    const float* Wo   = (const float*)d_in[15];
    const float* bo   = (const float*)d_in[16];
    const float* Wf1  = (const float*)d_in[17];
    const float* bf1  = (const float*)d_in[18];
    const float* Wf2  = (const float*)d_in[19];
    const float* bf2  = (const float*)d_in[20];
    const float* Wp   = (const float*)d_in[21];
    const float* bp   = (const float*)d_in[22];
    const float* gp   = (const float*)d_in[23];
    const float* bep  = (const float*)d_in[24];

    float* outf    = (float*)d_out;
    float* ws      = (float*)d_ws;
    float* filters = ws;                          // 2048 floats (pad 4096)
    float* G       = ws + 4096;                   // 1,048,576 floats (4 MB)
    float* stats   = ws + 4096 + 1048576;         // 589,824 floats (2.4 MB)
    float2* rowst  = (float2*)(ws + 4096 + 1048576 + 589824);  // 65536 float2
    float* xfp     = outf;                        // scratch 33.5 MB @ 0
    float* F       = outf + 16777216;             // scratch 4 MB @ 64 MB
                                                  // (d_out scratch dead before k4 writes)

    hipLaunchKernelGGL(k1_filters, dim3(B), dim3(1024), 0, stream,
                       ev, W1, b1, g1, be1, W2, b2, g2, be2,
                       Wqkv, bqkv, Wo, bo, Wf1, bf1, Wf2, bf2, filters);
    hipLaunchKernelGGL(k2_xfreq_partial, dim3(B * 16), dim3(256), 0, stream,
                       x, vg, xfp);
    hipLaunchKernelGGL(k2b_combine, dim3(1024), dim3(256), 0, stream,
                       xfp, filters, F);
    hipLaunchKernelGGL(k3_G, dim3(32 * 8), dim3(256), 0, stream,
                       F, Wp, G);
    hipLaunchKernelGGL(k3s_stats, dim3(B * 8), dim3(256), 0, stream,
                       G, bp, stats);
    hipLaunchKernelGGL(k3r_rowstats, dim3(B * 4), dim3(256), 0, stream,
                       vg, stats, rowst);
    hipLaunchKernelGGL(k4_out, dim3(B * 32), dim3(256), 0, stream,
                       vg, G, rowst, bp, gp, bep, outf);
}

// Round 12
// 140.156 us; speedup vs baseline: 1.0906x; 1.0906x over previous
//
#include <hip/hip_runtime.h>
#include <math.h>

#define B    64
#define NPG  1024
#define KEIG 32
#define DIN  512
#define DOUT 512
#define NPART 8   // k2 n-chunk partials

typedef float f32x4 __attribute__((ext_vector_type(4)));

__device__ __forceinline__ float rsum32(float v) {
    v += __shfl_xor(v, 1, 32);
    v += __shfl_xor(v, 2, 32);
    v += __shfl_xor(v, 4, 32);
    v += __shfl_xor(v, 8, 32);
    v += __shfl_xor(v, 16, 32);
    return v;
}
__device__ __forceinline__ float rmax32(float v) {
    v = fmaxf(v, __shfl_xor(v, 1, 32));
    v = fmaxf(v, __shfl_xor(v, 2, 32));
    v = fmaxf(v, __shfl_xor(v, 4, 32));
    v = fmaxf(v, __shfl_xor(v, 8, 32));
    v = fmaxf(v, __shfl_xor(v, 16, 32));
    return v;
}
__device__ __forceinline__ float rsum64(float v) {
    v += __shfl_xor(v, 1, 64);
    v += __shfl_xor(v, 2, 64);
    v += __shfl_xor(v, 4, 64);
    v += __shfl_xor(v, 8, 64);
    v += __shfl_xor(v, 16, 64);
    v += __shfl_xor(v, 32, 64);
    return v;
}

// ---------------------------------------------------------------------------
// Kernel 1: feature-parallel encoder + MHSA + filter head. (unchanged, ~8us)
// ---------------------------------------------------------------------------
__global__ __launch_bounds__(1024) void k1_filters(
    const float* __restrict__ eigenvalues,
    const float* __restrict__ W1,  const float* __restrict__ b1,
    const float* __restrict__ g1,  const float* __restrict__ be1,
    const float* __restrict__ W2,  const float* __restrict__ b2,
    const float* __restrict__ g2,  const float* __restrict__ be2,
    const float* __restrict__ Wqkv,const float* __restrict__ bqkv,
    const float* __restrict__ Wo,  const float* __restrict__ bo,
    const float* __restrict__ Wf1, const float* __restrict__ bf1,
    const float* __restrict__ Wf2, const float* __restrict__ bf2,
    float* __restrict__ filters)
{
    __shared__ float wts[224][33];
    __shared__ float hA[KEIG][33];
    __shared__ float hB[KEIG][33];
    __shared__ float qkv[KEIG][97];
    __shared__ float attn[4 * 1064];

    const int t = threadIdx.x;
    const int k = t >> 5;
    const int j = t & 31;
    const int b = blockIdx.x;

    {
        const int row = t >> 5, i = t & 31;
        wts[row][i]       = W2[t];
        wts[32 + row][i]  = Wqkv[t];
        wts[64 + row][i]  = Wqkv[1024 + t];
        wts[96 + row][i]  = Wqkv[2048 + t];
        wts[128 + row][i] = Wo[t];
        wts[160 + row][i] = Wf1[t];
        wts[192 + row][i] = Wf1[1024 + t];
    }

    const float ev = eigenvalues[b * KEIG + k];
    float h1 = ev * W1[j] + b1[j];
    {
        float m = rsum32(h1) * (1.f / 32.f);
        float d = h1 - m;
        float q = rsum32(d * d);
        float r = rsqrtf(q * (1.f / 32.f) + 1e-5f);
        h1 = fmaxf(d * r * g1[j] + be1[j], 0.f);
    }
    hA[k][j] = h1;
    __syncthreads();

    {
        float a = b2[j];
        #pragma unroll
        for (int i = 0; i < 32; ++i) a += hA[k][i] * wts[j][i];
        float m = rsum32(a) * (1.f / 32.f);
        float d = a - m;
        float q = rsum32(d * d);
        float r = rsqrtf(q * (1.f / 32.f) + 1e-5f);
        hB[k][j] = d * r * g2[j] + be2[j];
    }
    __syncthreads();

    {
        float aq = bqkv[j], ak = bqkv[32 + j], av = bqkv[64 + j];
        #pragma unroll
        for (int i = 0; i < 32; ++i) {
            float hv = hB[k][i];
            aq += hv * wts[32 + j][i];
            ak += hv * wts[64 + j][i];
            av += hv * wts[96 + j][i];
        }
        qkv[k][j]      = aq;
        qkv[k][32 + j] = ak;
        qkv[k][64 + j] = av;
    }
    __syncthreads();

    {
        const float inv = 0.35355339059327373f;
        float sc[4];
        #pragma unroll
        for (int hh = 0; hh < 4; ++hh) {
            float s = 0.f;
            #pragma unroll
            for (int d2 = 0; d2 < 8; ++d2)
                s += qkv[k][hh * 8 + d2] * qkv[j][32 + hh * 8 + d2];
            sc[hh] = s * inv;
        }
        #pragma unroll
        for (int hh = 0; hh < 4; ++hh) {
            float mx  = rmax32(sc[hh]);
            float e   = __expf(sc[hh] - mx);
            float den = rsum32(e);
            attn[hh * 1064 + k * 33 + j] = e / den;
        }
    }
    __syncthreads();

    {
        const int hh = j >> 3;
        float c = 0.f;
        #pragma unroll
        for (int k2 = 0; k2 < 32; ++k2)
            c += attn[hh * 1064 + k * 33 + k2] * qkv[k2][64 + j];
        hA[k][j] = c;
    }
    __syncthreads();

    {
        float o = bo[j];
        #pragma unroll
        for (int i = 0; i < 32; ++i) o += hA[k][i] * wts[128 + j][i];
        hB[k][j] = o;
    }
    __syncthreads();

    {
        float r0 = bf1[j], r1 = bf1[32 + j];
        #pragma unroll
        for (int i = 0; i < 32; ++i) {
            float ov = hB[k][i];
            r0 += ov * wts[160 + j][i];
            r1 += ov * wts[192 + j][i];
        }
        float fp = fmaxf(r0, 0.f) * Wf2[j] + fmaxf(r1, 0.f) * Wf2[32 + j];
        fp = rsum32(fp);
        if (j == 0) filters[b * KEIG + k] = tanhf(fp + bf2[0]);
    }
}

// ---------------------------------------------------------------------------
// Kernel 2: xfp[nc][b][k][d] = sum_{n in 128-row chunk} vg[n,k]*x[n,d]
// (unchanged; ~30us, near its 176MB traffic roofline)
// ---------------------------------------------------------------------------
__global__ __launch_bounds__(256) void k2_xfreq_partial(
    const float* __restrict__ x, const float* __restrict__ eigvec,
    float* __restrict__ xfp)
{
    __shared__ float vtile[128][32];
    const int t  = threadIdx.x;
    const int b  = blockIdx.x >> 4;
    const int nc = (blockIdx.x >> 1) & 7;
    const int dh = blockIdx.x & 1;
    const int kq = t >> 6;
    const int ds = t & 63;
    const int d  = dh * 256 + ds * 4;
    const int n0 = nc * 128;

    const float* vb = eigvec + ((size_t)(b * NPG + n0)) * KEIG;
    #pragma unroll
    for (int e = 0; e < 16; ++e) {
        int idx = t + e * 256;
        ((float*)vtile)[idx] = vb[idx];
    }
    __syncthreads();

    float4 acc[8];
    #pragma unroll
    for (int i = 0; i < 8; ++i) acc[i] = make_float4(0.f, 0.f, 0.f, 0.f);

    const float* xb = x + ((size_t)(b * NPG + n0)) * DIN + d;
    #pragma unroll 4
    for (int n = 0; n < 128; ++n) {
        float4 xv = *(const float4*)(xb + (size_t)n * DIN);
        const float4* vp = (const float4*)&vtile[n][kq * 8];
        float4 v0 = vp[0], v1 = vp[1];
        acc[0].x += v0.x * xv.x; acc[0].y += v0.x * xv.y; acc[0].z += v0.x * xv.z; acc[0].w += v0.x * xv.w;
        acc[1].x += v0.y * xv.x; acc[1].y += v0.y * xv.y; acc[1].z += v0.y * xv.z; acc[1].w += v0.y * xv.w;
        acc[2].x += v0.z * xv.x; acc[2].y += v0.z * xv.y; acc[2].z += v0.z * xv.z; acc[2].w += v0.z * xv.w;
        acc[3].x += v0.w * xv.x; acc[3].y += v0.w * xv.y; acc[3].z += v0.w * xv.z; acc[3].w += v0.w * xv.w;
        acc[4].x += v1.x * xv.x; acc[4].y += v1.x * xv.y; acc[4].z += v1.x * xv.z; acc[4].w += v1.x * xv.w;
        acc[5].x += v1.y * xv.x; acc[5].y += v1.y * xv.y; acc[5].z += v1.y * xv.z; acc[5].w += v1.y * xv.w;
        acc[6].x += v1.z * xv.x; acc[6].y += v1.z * xv.y; acc[6].z += v1.z * xv.z; acc[6].w += v1.z * xv.w;
        acc[7].x += v1.w * xv.x; acc[7].y += v1.w * xv.y; acc[7].z += v1.w * xv.z; acc[7].w += v1.w * xv.w;
    }

    #pragma unroll
    for (int kk = 0; kk < 8; ++kk) {
        int kg = kq * 8 + kk;
        *(float4*)(xfp + (((size_t)nc * B + b) * KEIG + kg) * DIN + d) = acc[kk];
    }
}

// ---------------------------------------------------------------------------
// Kernel 2b: F[m][d] = filters[m] * sum_nc xfp[nc][m][d].  (~7us)
// ---------------------------------------------------------------------------
__global__ __launch_bounds__(256) void k2b_combine(
    const float* __restrict__ xfp, const float* __restrict__ filters,
    float* __restrict__ F)
{
    const int t = threadIdx.x;
    const int m = blockIdx.x * 2 + (t >> 7);
    const int dp = (t & 127) * 4;

    const float* base = xfp + (size_t)m * DIN + dp;
    float4 s = *(const float4*)base;
    #pragma unroll
    for (int q = 1; q < NPART; ++q) {
        float4 sq = *(const float4*)(base + (size_t)q * (B * KEIG * DIN));
        s.x += sq.x; s.y += sq.y; s.z += sq.z; s.w += sq.w;
    }
    const float f = filters[m];
    float4 o = make_float4(s.x * f, s.y * f, s.z * f, s.w * f);
    *(float4*)(F + (size_t)m * DIN + dp) = o;
}

// ---------------------------------------------------------------------------
// Kernel 3: pure GEMM  G[m][o] = sum_d F[m][d] * Wp[o][d].  (~15us)
// ---------------------------------------------------------------------------
__global__ __launch_bounds__(256) void k3_G(
    const float* __restrict__ F, const float* __restrict__ Wp,
    float* __restrict__ G)
{
    __shared__ float a_lds[64][65];
    __shared__ float b_lds[64][65];

    const int t   = threadIdx.x;
    const int mt  = blockIdx.x >> 3;
    const int ot  = blockIdx.x & 7;
    const int m0  = mt * 64;
    const int o0  = ot * 64;
    const int tr  = t >> 4;
    const int tc  = t & 15;
    const int col4 = tc * 4;

    float acc[4][4] = {{0.f}};

    for (int d0 = 0; d0 < DIN; d0 += 64) {
        __syncthreads();
        #pragma unroll
        for (int p = 0; p < 4; ++p) {
            int r = p * 16 + tr;
            float4 s = *(const float4*)(F + (size_t)(m0 + r) * DIN + d0 + col4);
            a_lds[r][col4 + 0] = s.x;
            a_lds[r][col4 + 1] = s.y;
            a_lds[r][col4 + 2] = s.z;
            a_lds[r][col4 + 3] = s.w;
        }
        #pragma unroll
        for (int p = 0; p < 4; ++p) {
            int r = p * 16 + tr;
            float4 w = *(const float4*)(Wp + (size_t)(o0 + r) * DIN + d0 + col4);
            b_lds[r][col4 + 0] = w.x;
            b_lds[r][col4 + 1] = w.y;
            b_lds[r][col4 + 2] = w.z;
            b_lds[r][col4 + 3] = w.w;
        }
        __syncthreads();
        #pragma unroll 4
        for (int dd = 0; dd < 64; ++dd) {
            float a0 = a_lds[tr * 4 + 0][dd];
            float a1 = a_lds[tr * 4 + 1][dd];
            float a2 = a_lds[tr * 4 + 2][dd];
            float a3 = a_lds[tr * 4 + 3][dd];
            float b0 = b_lds[tc * 4 + 0][dd];
            float b1 = b_lds[tc * 4 + 1][dd];
            float b2 = b_lds[tc * 4 + 2][dd];
            float b3 = b_lds[tc * 4 + 3][dd];
            acc[0][0] += a0 * b0; acc[0][1] += a0 * b1; acc[0][2] += a0 * b2; acc[0][3] += a0 * b3;
            acc[1][0] += a1 * b0; acc[1][1] += a1 * b1; acc[1][2] += a1 * b2; acc[1][3] += a1 * b3;
            acc[2][0] += a2 * b0; acc[2][1] += a2 * b1; acc[2][2] += a2 * b2; acc[2][3] += a2 * b3;
            acc[3][0] += a3 * b0; acc[3][1] += a3 * b1; acc[3][2] += a3 * b2; acc[3][3] += a3 * b3;
        }
    }
    #pragma unroll
    for (int i = 0; i < 4; ++i) {
        float4 v = make_float4(acc[i][0], acc[i][1], acc[i][2], acc[i][3]);
        *(float4*)(G + (size_t)(m0 + tr * 4 + i) * DOUT + o0 + col4) = v;
    }
}

// ---------------------------------------------------------------------------
// Kernel 4 (v10): out[n,:] = LN( vg[n,:] @ G[b] + bp ) * gp + bep
// grid = B*16 = 1024 blocks, 256 thr = 4 waves x 16 rows, single pass.
// LDS-minimal inner loop: per k only ga+gb (2 b128); the 16 per-row vg
// scalars come via VMEM broadcast loads (all lanes same addr -> 1 L1
// transaction, OFF the LDS pipe). 64 LDS instr/thread vs v3's 192 vs
// v6's 384 — the only knob that ever moved k4 (fit: t ~ 50us + LDS-pipe).
// k-loop chunked (8 x 4k), NOT unrolled: ~4.5KB body, compiler pipelines
// next chunk's 16 loads against current 512 FMAs. Wave-local shfl LN.
// ---------------------------------------------------------------------------
__global__ __launch_bounds__(256, 2) void k4_out(
    const float* __restrict__ eigvec, const float* __restrict__ G,
    const float* __restrict__ bp, const float* __restrict__ gp,
    const float* __restrict__ bep, float* __restrict__ out)
{
    __shared__ float gsh[KEIG][DOUT];   // 64 KB

    const int t  = threadIdx.x;
    const int b  = blockIdx.x >> 4;
    const int n0 = (blockIdx.x & 15) * 64;

    // stage G[b] (64 KB, coalesced float4)
    const float4* G4 = (const float4*)(G + (size_t)b * KEIG * DOUT);
    float4* gsh4 = (float4*)gsh;
    #pragma unroll
    for (int e = 0; e < 16; ++e)
        gsh4[t + e * 256] = G4[t + e * 256];
    __syncthreads();   // the ONLY barrier

    const int w     = t >> 6;
    const int l     = t & 63;
    const int c0    = 4 * l;       // cols c0..c0+3 and 256+c0..+3
    const int rbase = w * 16;      // this wave's 16 local rows

    const float4 bpA = *(const float4*)(bp + c0);
    const float4 bpB = *(const float4*)(bp + 256 + c0);

    float4 aA[16], aB[16];
    #pragma unroll
    for (int r = 0; r < 16; ++r) { aA[r] = bpA; aB[r] = bpB; }

    const float* vrow = eigvec + ((size_t)(b * NPG + n0 + rbase)) * KEIG;

    for (int kc = 0; kc < 8; ++kc) {          // 8 chunks of 4 k's
        // vg broadcast loads: wave-uniform addresses, 16 independent VMEM ops
        float4 vgr[16];
        #pragma unroll
        for (int r = 0; r < 16; ++r)
            vgr[r] = *(const float4*)(vrow + (size_t)r * KEIG + kc * 4);

        #pragma unroll
        for (int kk = 0; kk < 4; ++kk) {
            const int k = kc * 4 + kk;
            const float4 ga = *(const float4*)&gsh[k][c0];
            const float4 gb = *(const float4*)&gsh[k][256 + c0];
            #pragma unroll
            for (int r = 0; r < 16; ++r) {
                const float vv = (kk == 0) ? vgr[r].x :
                                 (kk == 1) ? vgr[r].y :
                                 (kk == 2) ? vgr[r].z : vgr[r].w;
                aA[r].x = fmaf(vv, ga.x, aA[r].x);
                aA[r].y = fmaf(vv, ga.y, aA[r].y);
                aA[r].z = fmaf(vv, ga.z, aA[r].z);
                aA[r].w = fmaf(vv, ga.w, aA[r].w);
                aB[r].x = fmaf(vv, gb.x, aB[r].x);
                aB[r].y = fmaf(vv, gb.y, aB[r].y);
                aB[r].z = fmaf(vv, gb.z, aB[r].z);
                aB[r].w = fmaf(vv, gb.w, aB[r].w);
            }
        }
    }

    // epilogue: LN (wave-local shfl over the 64 lanes = full 512-col row)
    const float4 gpA = *(const float4*)(gp + c0);
    const float4 gpB = *(const float4*)(gp + 256 + c0);
    const float4 beA = *(const float4*)(bep + c0);
    const float4 beB = *(const float4*)(bep + 256 + c0);

    #pragma unroll
    for (int r = 0; r < 16; ++r) {
        float s = aA[r].x + aA[r].y + aA[r].z + aA[r].w
                + aB[r].x + aB[r].y + aB[r].z + aB[r].w;
        float q = aA[r].x * aA[r].x + aA[r].y * aA[r].y
                + aA[r].z * aA[r].z + aA[r].w * aA[r].w
                + aB[r].x * aB[r].x + aB[r].y * aB[r].y
                + aB[r].z * aB[r].z + aB[r].w * aB[r].w;
        s = rsum64(s);
        q = rsum64(q);
        float m    = s * (1.f / 512.f);
        float rstd = rsqrtf(q * (1.f / 512.f) - m * m + 1e-5f);

        float4 oA, oB;
        oA.x = (aA[r].x - m) * rstd * gpA.x + beA.x;
        oA.y = (aA[r].y - m) * rstd * gpA.y + beA.y;
        oA.z = (aA[r].z - m) * rstd * gpA.z + beA.z;
        oA.w = (aA[r].w - m) * rstd * gpA.w + beA.w;
        oB.x = (aB[r].x - m) * rstd * gpB.x + beB.x;
        oB.y = (aB[r].y - m) * rstd * gpB.y + beB.y;
        oB.z = (aB[r].z - m) * rstd * gpB.z + beB.z;
        oB.w = (aB[r].w - m) * rstd * gpB.w + beB.w;

        size_t row = (size_t)b * NPG + n0 + rbase + r;
        *(float4*)(out + row * DOUT + c0)       = oA;
        *(float4*)(out + row * DOUT + 256 + c0) = oB;
    }
}

// ---------------------------------------------------------------------------
extern "C" void kernel_launch(void* const* d_in, const int* in_sizes, int n_in,
                              void* d_out, int out_size, void* d_ws, size_t ws_size,
                              hipStream_t stream) {
    (void)in_sizes; (void)n_in; (void)out_size; (void)ws_size;
    const float* x    = (const float*)d_in[0];
    const float* vg   = (const float*)d_in[1];
    const float* ev   = (const float*)d_in[2];
    const float* W1   = (const float*)d_in[5];
    const float* b1   = (const float*)d_in[6];
    const float* g1   = (const float*)d_in[7];
    const float* be1  = (const float*)d_in[8];
    const float* W2   = (const float*)d_in[9];
    const float* b2   = (const float*)d_in[10];
    const float* g2   = (const float*)d_in[11];
    const float* be2  = (const float*)d_in[12];
    const float* Wqkv = (const float*)d_in[13];
    const float* bqkv = (const float*)d_in[14];
    const float* Wo   = (const float*)d_in[15];
    const float* bo   = (const float*)d_in[16];
    const float* Wf1  = (const float*)d_in[17];
    const float* bf1  = (const float*)d_in[18];
    const float* Wf2  = (const float*)d_in[19];
    const float* bf2  = (const float*)d_in[20];
    const float* Wp   = (const float*)d_in[21];
    const float* bp   = (const float*)d_in[22];
    const float* gp   = (const float*)d_in[23];
    const float* bep  = (const float*)d_in[24];

    float* outf    = (float*)d_out;
    float* ws      = (float*)d_ws;
    float* filters = ws;                         // 2048 floats
    float* G       = ws + 4096;                  // 1,048,576 floats (4 MB)
    float* xfp     = outf;                       // scratch: 33.5 MB at offset 0
    float* F       = outf + 16777216;            // scratch: 4 MB at 64 MB offset
                                                 // (both overwritten by k4)

    hipLaunchKernelGGL(k1_filters, dim3(B), dim3(1024), 0, stream,
                       ev, W1, b1, g1, be1, W2, b2, g2, be2,
                       Wqkv, bqkv, Wo, bo, Wf1, bf1, Wf2, bf2, filters);
    hipLaunchKernelGGL(k2_xfreq_partial, dim3(B * 16), dim3(256), 0, stream,
                       x, vg, xfp);
    hipLaunchKernelGGL(k2b_combine, dim3(1024), dim3(256), 0, stream,
                       xfp, filters, F);
    hipLaunchKernelGGL(k3_G, dim3(32 * 8), dim3(256), 0, stream,
                       F, Wp, G);
    hipLaunchKernelGGL(k4_out, dim3(B * 16), dim3(256), 0, stream,
                       vg, G, bp, gp, bep, outf);
}

// Round 13
// 130.477 us; speedup vs baseline: 1.1715x; 1.0742x over previous
//
#include <hip/hip_runtime.h>
#include <math.h>

#define B    64
#define NPG  1024
#define KEIG 32
#define DIN  512
#define DOUT 512
#define NPART 8   // k2 n-chunk partials

typedef float f32x4 __attribute__((ext_vector_type(4)));   // native vec for NT stores

__device__ __forceinline__ float rsum32(float v) {
    v += __shfl_xor(v, 1, 32);
    v += __shfl_xor(v, 2, 32);
    v += __shfl_xor(v, 4, 32);
    v += __shfl_xor(v, 8, 32);
    v += __shfl_xor(v, 16, 32);
    return v;
}
__device__ __forceinline__ float rmax32(float v) {
    v = fmaxf(v, __shfl_xor(v, 1, 32));
    v = fmaxf(v, __shfl_xor(v, 2, 32));
    v = fmaxf(v, __shfl_xor(v, 4, 32));
    v = fmaxf(v, __shfl_xor(v, 8, 32));
    v = fmaxf(v, __shfl_xor(v, 16, 32));
    return v;
}
__device__ __forceinline__ float rsum64(float v) {
    v += __shfl_xor(v, 1, 64);
    v += __shfl_xor(v, 2, 64);
    v += __shfl_xor(v, 4, 64);
    v += __shfl_xor(v, 8, 64);
    v += __shfl_xor(v, 16, 64);
    v += __shfl_xor(v, 32, 64);
    return v;
}

// ---------------------------------------------------------------------------
// Kernel 1: feature-parallel encoder + MHSA + filter head. (~8us)
// ---------------------------------------------------------------------------
__global__ __launch_bounds__(1024) void k1_filters(
    const float* __restrict__ eigenvalues,
    const float* __restrict__ W1,  const float* __restrict__ b1,
    const float* __restrict__ g1,  const float* __restrict__ be1,
    const float* __restrict__ W2,  const float* __restrict__ b2,
    const float* __restrict__ g2,  const float* __restrict__ be2,
    const float* __restrict__ Wqkv,const float* __restrict__ bqkv,
    const float* __restrict__ Wo,  const float* __restrict__ bo,
    const float* __restrict__ Wf1, const float* __restrict__ bf1,
    const float* __restrict__ Wf2, const float* __restrict__ bf2,
    float* __restrict__ filters)
{
    __shared__ float wts[224][33];
    __shared__ float hA[KEIG][33];
    __shared__ float hB[KEIG][33];
    __shared__ float qkv[KEIG][97];
    __shared__ float attn[4 * 1064];

    const int t = threadIdx.x;
    const int k = t >> 5;
    const int j = t & 31;
    const int b = blockIdx.x;

    {
        const int row = t >> 5, i = t & 31;
        wts[row][i]       = W2[t];
        wts[32 + row][i]  = Wqkv[t];
        wts[64 + row][i]  = Wqkv[1024 + t];
        wts[96 + row][i]  = Wqkv[2048 + t];
        wts[128 + row][i] = Wo[t];
        wts[160 + row][i] = Wf1[t];
        wts[192 + row][i] = Wf1[1024 + t];
    }

    const float ev = eigenvalues[b * KEIG + k];
    float h1 = ev * W1[j] + b1[j];
    {
        float m = rsum32(h1) * (1.f / 32.f);
        float d = h1 - m;
        float q = rsum32(d * d);
        float r = rsqrtf(q * (1.f / 32.f) + 1e-5f);
        h1 = fmaxf(d * r * g1[j] + be1[j], 0.f);
    }
    hA[k][j] = h1;
    __syncthreads();

    {
        float a = b2[j];
        #pragma unroll
        for (int i = 0; i < 32; ++i) a += hA[k][i] * wts[j][i];
        float m = rsum32(a) * (1.f / 32.f);
        float d = a - m;
        float q = rsum32(d * d);
        float r = rsqrtf(q * (1.f / 32.f) + 1e-5f);
        hB[k][j] = d * r * g2[j] + be2[j];
    }
    __syncthreads();

    {
        float aq = bqkv[j], ak = bqkv[32 + j], av = bqkv[64 + j];
        #pragma unroll
        for (int i = 0; i < 32; ++i) {
            float hv = hB[k][i];
            aq += hv * wts[32 + j][i];
            ak += hv * wts[64 + j][i];
            av += hv * wts[96 + j][i];
        }
        qkv[k][j]      = aq;
        qkv[k][32 + j] = ak;
        qkv[k][64 + j] = av;
    }
    __syncthreads();

    {
        const float inv = 0.35355339059327373f;
        float sc[4];
        #pragma unroll
        for (int hh = 0; hh < 4; ++hh) {
            float s = 0.f;
            #pragma unroll
            for (int d2 = 0; d2 < 8; ++d2)
                s += qkv[k][hh * 8 + d2] * qkv[j][32 + hh * 8 + d2];
            sc[hh] = s * inv;
        }
        #pragma unroll
        for (int hh = 0; hh < 4; ++hh) {
            float mx  = rmax32(sc[hh]);
            float e   = __expf(sc[hh] - mx);
            float den = rsum32(e);
            attn[hh * 1064 + k * 33 + j] = e / den;
        }
    }
    __syncthreads();

    {
        const int hh = j >> 3;
        float c = 0.f;
        #pragma unroll
        for (int k2 = 0; k2 < 32; ++k2)
            c += attn[hh * 1064 + k * 33 + k2] * qkv[k2][64 + j];
        hA[k][j] = c;
    }
    __syncthreads();

    {
        float o = bo[j];
        #pragma unroll
        for (int i = 0; i < 32; ++i) o += hA[k][i] * wts[128 + j][i];
        hB[k][j] = o;
    }
    __syncthreads();

    {
        float r0 = bf1[j], r1 = bf1[32 + j];
        #pragma unroll
        for (int i = 0; i < 32; ++i) {
            float ov = hB[k][i];
            r0 += ov * wts[160 + j][i];
            r1 += ov * wts[192 + j][i];
        }
        float fp = fmaxf(r0, 0.f) * Wf2[j] + fmaxf(r1, 0.f) * Wf2[32 + j];
        fp = rsum32(fp);
        if (j == 0) filters[b * KEIG + k] = tanhf(fp + bf2[0]);
    }
}

// ---------------------------------------------------------------------------
// Kernel 2: xfp[nc][b][k][d] = sum_{n in 128-row chunk} vg[n,k]*x[n,d]
// (~30us; near its 176MB traffic roofline)
// ---------------------------------------------------------------------------
__global__ __launch_bounds__(256) void k2_xfreq_partial(
    const float* __restrict__ x, const float* __restrict__ eigvec,
    float* __restrict__ xfp)
{
    __shared__ float vtile[128][32];
    const int t  = threadIdx.x;
    const int b  = blockIdx.x >> 4;
    const int nc = (blockIdx.x >> 1) & 7;
    const int dh = blockIdx.x & 1;
    const int kq = t >> 6;
    const int ds = t & 63;
    const int d  = dh * 256 + ds * 4;
    const int n0 = nc * 128;

    const float* vb = eigvec + ((size_t)(b * NPG + n0)) * KEIG;
    #pragma unroll
    for (int e = 0; e < 16; ++e) {
        int idx = t + e * 256;
        ((float*)vtile)[idx] = vb[idx];
    }
    __syncthreads();

    float4 acc[8];
    #pragma unroll
    for (int i = 0; i < 8; ++i) acc[i] = make_float4(0.f, 0.f, 0.f, 0.f);

    const float* xb = x + ((size_t)(b * NPG + n0)) * DIN + d;
    #pragma unroll 4
    for (int n = 0; n < 128; ++n) {
        float4 xv = *(const float4*)(xb + (size_t)n * DIN);
        const float4* vp = (const float4*)&vtile[n][kq * 8];
        float4 v0 = vp[0], v1 = vp[1];
        acc[0].x += v0.x * xv.x; acc[0].y += v0.x * xv.y; acc[0].z += v0.x * xv.z; acc[0].w += v0.x * xv.w;
        acc[1].x += v0.y * xv.x; acc[1].y += v0.y * xv.y; acc[1].z += v0.y * xv.z; acc[1].w += v0.y * xv.w;
        acc[2].x += v0.z * xv.x; acc[2].y += v0.z * xv.y; acc[2].z += v0.z * xv.z; acc[2].w += v0.z * xv.w;
        acc[3].x += v0.w * xv.x; acc[3].y += v0.w * xv.y; acc[3].z += v0.w * xv.z; acc[3].w += v0.w * xv.w;
        acc[4].x += v1.x * xv.x; acc[4].y += v1.x * xv.y; acc[4].z += v1.x * xv.z; acc[4].w += v1.x * xv.w;
        acc[5].x += v1.y * xv.x; acc[5].y += v1.y * xv.y; acc[5].z += v1.y * xv.z; acc[5].w += v1.y * xv.w;
        acc[6].x += v1.z * xv.x; acc[6].y += v1.z * xv.y; acc[6].z += v1.z * xv.z; acc[6].w += v1.z * xv.w;
        acc[7].x += v1.w * xv.x; acc[7].y += v1.w * xv.y; acc[7].z += v1.w * xv.z; acc[7].w += v1.w * xv.w;
    }

    #pragma unroll
    for (int kk = 0; kk < 8; ++kk) {
        int kg = kq * 8 + kk;
        *(float4*)(xfp + (((size_t)nc * B + b) * KEIG + kg) * DIN + d) = acc[kk];
    }
}

// ---------------------------------------------------------------------------
// Kernel 2b: F[m][d] = filters[m] * sum_nc xfp[nc][m][d].  (~7us)
// ---------------------------------------------------------------------------
__global__ __launch_bounds__(256) void k2b_combine(
    const float* __restrict__ xfp, const float* __restrict__ filters,
    float* __restrict__ F)
{
    const int t = threadIdx.x;
    const int m = blockIdx.x * 2 + (t >> 7);
    const int dp = (t & 127) * 4;

    const float* base = xfp + (size_t)m * DIN + dp;
    float4 s = *(const float4*)base;
    #pragma unroll
    for (int q = 1; q < NPART; ++q) {
        float4 sq = *(const float4*)(base + (size_t)q * (B * KEIG * DIN));
        s.x += sq.x; s.y += sq.y; s.z += sq.z; s.w += sq.w;
    }
    const float f = filters[m];
    float4 o = make_float4(s.x * f, s.y * f, s.z * f, s.w * f);
    *(float4*)(F + (size_t)m * DIN + dp) = o;
}

// ---------------------------------------------------------------------------
// Kernel 3: pure GEMM  G[m][o] = sum_d F[m][d] * Wp[o][d].  (~15us)
// ---------------------------------------------------------------------------
__global__ __launch_bounds__(256) void k3_G(
    const float* __restrict__ F, const float* __restrict__ Wp,
    float* __restrict__ G)
{
    __shared__ float a_lds[64][65];
    __shared__ float b_lds[64][65];

    const int t   = threadIdx.x;
    const int mt  = blockIdx.x >> 3;
    const int ot  = blockIdx.x & 7;
    const int m0  = mt * 64;
    const int o0  = ot * 64;
    const int tr  = t >> 4;
    const int tc  = t & 15;
    const int col4 = tc * 4;

    float acc[4][4] = {{0.f}};

    for (int d0 = 0; d0 < DIN; d0 += 64) {
        __syncthreads();
        #pragma unroll
        for (int p = 0; p < 4; ++p) {
            int r = p * 16 + tr;
            float4 s = *(const float4*)(F + (size_t)(m0 + r) * DIN + d0 + col4);
            a_lds[r][col4 + 0] = s.x;
            a_lds[r][col4 + 1] = s.y;
            a_lds[r][col4 + 2] = s.z;
            a_lds[r][col4 + 3] = s.w;
        }
        #pragma unroll
        for (int p = 0; p < 4; ++p) {
            int r = p * 16 + tr;
            float4 w = *(const float4*)(Wp + (size_t)(o0 + r) * DIN + d0 + col4);
            b_lds[r][col4 + 0] = w.x;
            b_lds[r][col4 + 1] = w.y;
            b_lds[r][col4 + 2] = w.z;
            b_lds[r][col4 + 3] = w.w;
        }
        __syncthreads();
        #pragma unroll 4
        for (int dd = 0; dd < 64; ++dd) {
            float a0 = a_lds[tr * 4 + 0][dd];
            float a1 = a_lds[tr * 4 + 1][dd];
            float a2 = a_lds[tr * 4 + 2][dd];
            float a3 = a_lds[tr * 4 + 3][dd];
            float b0 = b_lds[tc * 4 + 0][dd];
            float b1 = b_lds[tc * 4 + 1][dd];
            float b2 = b_lds[tc * 4 + 2][dd];
            float b3 = b_lds[tc * 4 + 3][dd];
            acc[0][0] += a0 * b0; acc[0][1] += a0 * b1; acc[0][2] += a0 * b2; acc[0][3] += a0 * b3;
            acc[1][0] += a1 * b0; acc[1][1] += a1 * b1; acc[1][2] += a1 * b2; acc[1][3] += a1 * b3;
            acc[2][0] += a2 * b0; acc[2][1] += a2 * b1; acc[2][2] += a2 * b2; acc[2][3] += a2 * b3;
            acc[3][0] += a3 * b0; acc[3][1] += a3 * b1; acc[3][2] += a3 * b2; acc[3][3] += a3 * b3;
        }
    }
    #pragma unroll
    for (int i = 0; i < 4; ++i) {
        float4 v = make_float4(acc[i][0], acc[i][1], acc[i][2], acc[i][3]);
        *(float4*)(G + (size_t)(m0 + tr * 4 + i) * DOUT + o0 + col4) = v;
    }
}

// ---------------------------------------------------------------------------
// Kernel 4 (v3 — best measured, 130.3/131.0 us totals):
// out[n,:] = LN( vg[n,:] @ G[b] + bp ) * gp + bep
// grid = B*16 = 1024 blocks, 256 thr = 4 waves; wave owns 16 FULL rows in
// ONE pass: per k-iter 2 b128 G-reads + 4 broadcast b128 vg-reads feed
// 128 FMAs. acc = 128 VGPR; launch_bounds(256,2). Wave-local shfl LN,
// NT stores. Seven probed alternatives (occupancy 2x, G-from-L2, plain
// stores, col-split+analytic-LN, VMEM-broadcast vg) all measured equal
// or worse — this is the empirical floor configuration.
// ---------------------------------------------------------------------------
__global__ __launch_bounds__(256, 2) void k4_out(
    const float* __restrict__ eigvec, const float* __restrict__ G,
    const float* __restrict__ bp, const float* __restrict__ gp,
    const float* __restrict__ bep, float* __restrict__ out)
{
    __shared__ float gsh[KEIG][DOUT];   // 64 KB
    __shared__ float vgt[KEIG][68];     // vg tile transposed [k][row], padded

    const int t  = threadIdx.x;
    const int b  = blockIdx.x >> 4;
    const int n0 = (blockIdx.x & 15) * 64;

    // stage G[b] (64 KB, coalesced float4)
    const float4* G4 = (const float4*)(G + (size_t)b * KEIG * DOUT);
    float4* gsh4 = (float4*)gsh;
    #pragma unroll
    for (int e = 0; e < 16; ++e)
        gsh4[t + e * 256] = G4[t + e * 256];

    // stage vg rows n0..n0+63 transposed
    const float* vb = eigvec + ((size_t)(b * NPG + n0)) * KEIG;
    #pragma unroll
    for (int e = 0; e < 8; ++e) {
        int idx = t + e * 256;
        vgt[idx & 31][idx >> 5] = vb[idx];
    }
    __syncthreads();   // the ONLY barrier

    const int w     = t >> 6;
    const int l     = t & 63;
    const int c0    = 4 * l;       // cols c0..c0+3 and 256+c0..+3
    const int rbase = w * 16;      // this wave's 16 local rows

    const float4 bpA = *(const float4*)(bp + c0);
    const float4 bpB = *(const float4*)(bp + 256 + c0);
    const float4 gpA = *(const float4*)(gp + c0);
    const float4 gpB = *(const float4*)(gp + 256 + c0);
    const float4 beA = *(const float4*)(bep + c0);
    const float4 beB = *(const float4*)(bep + 256 + c0);

    float4 aA[16], aB[16];
    #pragma unroll
    for (int r = 0; r < 16; ++r) { aA[r] = bpA; aB[r] = bpB; }

    for (int k = 0; k < KEIG; ++k) {
        const float4 ga = *(const float4*)&gsh[k][c0];
        const float4 gb = *(const float4*)&gsh[k][256 + c0];
        const float4 v0 = *(const float4*)&vgt[k][rbase];
        const float4 v1 = *(const float4*)&vgt[k][rbase + 4];
        const float4 v2 = *(const float4*)&vgt[k][rbase + 8];
        const float4 v3 = *(const float4*)&vgt[k][rbase + 12];
        const float vr[16] = {v0.x,v0.y,v0.z,v0.w, v1.x,v1.y,v1.z,v1.w,
                              v2.x,v2.y,v2.z,v2.w, v3.x,v3.y,v3.z,v3.w};
        #pragma unroll
        for (int r = 0; r < 16; ++r) {
            aA[r].x += vr[r] * ga.x; aA[r].y += vr[r] * ga.y;
            aA[r].z += vr[r] * ga.z; aA[r].w += vr[r] * ga.w;
            aB[r].x += vr[r] * gb.x; aB[r].y += vr[r] * gb.y;
            aB[r].z += vr[r] * gb.z; aB[r].w += vr[r] * gb.w;
        }
    }

    #pragma unroll
    for (int r = 0; r < 16; ++r) {
        float s = aA[r].x + aA[r].y + aA[r].z + aA[r].w
                + aB[r].x + aB[r].y + aB[r].z + aB[r].w;
        float q = aA[r].x * aA[r].x + aA[r].y * aA[r].y
                + aA[r].z * aA[r].z + aA[r].w * aA[r].w
                + aB[r].x * aB[r].x + aB[r].y * aB[r].y
                + aB[r].z * aB[r].z + aB[r].w * aB[r].w;
        s = rsum64(s);
        q = rsum64(q);
        float m    = s * (1.f / 512.f);
        float rstd = rsqrtf(q * (1.f / 512.f) - m * m + 1e-5f);

        f32x4 oA, oB;
        oA.x = (aA[r].x - m) * rstd * gpA.x + beA.x;
        oA.y = (aA[r].y - m) * rstd * gpA.y + beA.y;
        oA.z = (aA[r].z - m) * rstd * gpA.z + beA.z;
        oA.w = (aA[r].w - m) * rstd * gpA.w + beA.w;
        oB.x = (aB[r].x - m) * rstd * gpB.x + beB.x;
        oB.y = (aB[r].y - m) * rstd * gpB.y + beB.y;
        oB.z = (aB[r].z - m) * rstd * gpB.z + beB.z;
        oB.w = (aB[r].w - m) * rstd * gpB.w + beB.w;

        size_t row = (size_t)b * NPG + n0 + rbase + r;
        __builtin_nontemporal_store(oA, (f32x4*)(out + row * DOUT + c0));
        __builtin_nontemporal_store(oB, (f32x4*)(out + row * DOUT + 256 + c0));
    }
}

// ---------------------------------------------------------------------------
extern "C" void kernel_launch(void* const* d_in, const int* in_sizes, int n_in,
                              void* d_out, int out_size, void* d_ws, size_t ws_size,
                              hipStream_t stream) {
    (void)in_sizes; (void)n_in; (void)out_size; (void)ws_size;
    const float* x    = (const float*)d_in[0];
    const float* vg   = (const float*)d_in[1];
    const float* ev   = (const float*)d_in[2];
    const float* W1   = (const float*)d_in[5];
    const float* b1   = (const float*)d_in[6];
    const float* g1   = (const float*)d_in[7];
    const float* be1  = (const float*)d_in[8];
    const float* W2   = (const float*)d_in[9];
    const float* b2   = (const float*)d_in[10];
    const float* g2   = (const float*)d_in[11];
    const float* be2  = (const float*)d_in[12];
    const float* Wqkv = (const float*)d_in[13];
    const float* bqkv = (const float*)d_in[14];
    const float* Wo   = (const float*)d_in[15];
    const float* bo   = (const float*)d_in[16];
    const float* Wf1  = (const float*)d_in[17];
    const float* bf1  = (const float*)d_in[18];
    const float* Wf2  = (const float*)d_in[19];
    const float* bf2  = (const float*)d_in[20];
    const float* Wp   = (const float*)d_in[21];
    const float* bp   = (const float*)d_in[22];
    const float* gp   = (const float*)d_in[23];
    const float* bep  = (const float*)d_in[24];

    float* outf    = (float*)d_out;
    float* ws      = (float*)d_ws;
    float* filters = ws;                         // 2048 floats
    float* G       = ws + 4096;                  // 1,048,576 floats (4 MB)
    float* xfp     = outf;                       // scratch: 33.5 MB at offset 0
    float* F       = outf + 16777216;            // scratch: 4 MB at 64 MB offset
                                                 // (both overwritten by k4)

    hipLaunchKernelGGL(k1_filters, dim3(B), dim3(1024), 0, stream,
                       ev, W1, b1, g1, be1, W2, b2, g2, be2,
                       Wqkv, bqkv, Wo, bo, Wf1, bf1, Wf2, bf2, filters);
    hipLaunchKernelGGL(k2_xfreq_partial, dim3(B * 16), dim3(256), 0, stream,
                       x, vg, xfp);
    hipLaunchKernelGGL(k2b_combine, dim3(1024), dim3(256), 0, stream,
                       xfp, filters, F);
    hipLaunchKernelGGL(k3_G, dim3(32 * 8), dim3(256), 0, stream,
                       F, Wp, G);
    hipLaunchKernelGGL(k4_out, dim3(B * 16), dim3(256), 0, stream,
                       vg, G, bp, gp, bep, outf);
}